// Round 1
// baseline (24979.619 us; speedup 1.0000x reference)
//
#include <hip/hip_runtime.h>
#include <cstddef>

// ---------------------------------------------------------------------------
// Problem constants (from reference setup_inputs)
// ---------------------------------------------------------------------------
#define BB   8
#define LL   60
#define FF   13
#define DM   768
#define II   1536
#define NN   16
#define RR   48
#define KK   4
#define NL   32
#define ROWS (BB * LL)          // 480

// ---------------------------------------------------------------------------
// Generic fp32 tiled GEMM: C = act(A@B + bias) (+ Cadd)
// A: M x K (row stride lda), B: K x N (contig), C/Cadd: M x N (contig)
// act: 0=none, 1=relu, 2=softplus
// 64x64 tile, BK=16, 256 threads, 4x4 micro-tile
// ---------------------------------------------------------------------------
__global__ __launch_bounds__(256) void gemm_f32(
    const float* __restrict__ A, int lda,
    const float* __restrict__ B,
    float* __restrict__ C,
    const float* __restrict__ Cadd,
    const float* __restrict__ bias,
    int M, int N, int K, int act)
{
    __shared__ float As[16][68];   // [k][m], +4 pad keeps 16B alignment for b128 reads
    __shared__ float Bs[16][64];   // [k][n]
    const int tid  = threadIdx.x;
    const int tx   = tid & 15;     // 16 col-groups
    const int ty   = tid >> 4;     // 16 row-groups
    const int row0 = blockIdx.y * 64;
    const int col0 = blockIdx.x * 64;

    float acc[4][4] = {};

    for (int k0 = 0; k0 < K; k0 += 16) {
        // A tile 64x16 -> As[k][m]; adjacent tids load adjacent k (coalesced 64B)
        #pragma unroll
        for (int p = 0; p < 4; ++p) {
            int m  = ty + 16 * p;
            int gm = row0 + m, gk = k0 + tx;
            As[tx][m] = (gm < M && gk < K) ? A[(size_t)gm * lda + gk] : 0.f;
        }
        // B tile 16x64 -> Bs[k][n]; adjacent tids load adjacent n (coalesced)
        #pragma unroll
        for (int p = 0; p < 4; ++p) {
            int k  = (tid >> 6) + 4 * p;
            int n  = tid & 63;
            int gk = k0 + k, gn = col0 + n;
            Bs[k][n] = (gk < K && gn < N) ? B[(size_t)gk * N + gn] : 0.f;
        }
        __syncthreads();
        #pragma unroll
        for (int k = 0; k < 16; ++k) {
            float am[4], bn[4];
            #pragma unroll
            for (int i = 0; i < 4; ++i) am[i] = As[k][ty * 4 + i];
            #pragma unroll
            for (int j = 0; j < 4; ++j) bn[j] = Bs[k][tx * 4 + j];
            #pragma unroll
            for (int i = 0; i < 4; ++i)
                #pragma unroll
                for (int j = 0; j < 4; ++j)
                    acc[i][j] = fmaf(am[i], bn[j], acc[i][j]);
        }
        __syncthreads();
    }

    #pragma unroll
    for (int i = 0; i < 4; ++i) {
        int gm = row0 + ty * 4 + i;
        if (gm >= M) continue;
        #pragma unroll
        for (int j = 0; j < 4; ++j) {
            int gn = col0 + tx * 4 + j;
            if (gn >= N) continue;
            float v = acc[i][j];
            if (bias) v += bias[gn];
            if (act == 1)      v = fmaxf(v, 0.f);
            else if (act == 2) v = (v > 20.f) ? v : log1pf(expf(v));  // softplus
            if (Cadd) v += Cadd[(size_t)gm * N + gn];
            C[(size_t)gm * N + gn] = v;
        }
    }
}

// ---------------------------------------------------------------------------
// RMSNorm: out[row] = x[row] * rsqrt(mean(x^2)+eps) * w   (one block per row)
// ---------------------------------------------------------------------------
__global__ __launch_bounds__(256) void rmsnorm_k(
    const float* __restrict__ x, const float* __restrict__ w,
    float* __restrict__ out, int D)
{
    const int row = blockIdx.x;
    const float* xr = x + (size_t)row * D;
    float* orow = out + (size_t)row * D;

    float ss = 0.f;
    for (int j = threadIdx.x; j < D; j += 256) { float v = xr[j]; ss = fmaf(v, v, ss); }
    #pragma unroll
    for (int off = 32; off > 0; off >>= 1) ss += __shfl_down(ss, off, 64);
    __shared__ float wsum[4];
    __shared__ float rstd_s;
    if ((threadIdx.x & 63) == 0) wsum[threadIdx.x >> 6] = ss;
    __syncthreads();
    if (threadIdx.x == 0) {
        float t = wsum[0] + wsum[1] + wsum[2] + wsum[3];
        rstd_s = 1.f / sqrtf(t / (float)D + 1e-5f);
    }
    __syncthreads();
    const float r = rstd_s;
    for (int j = threadIdx.x; j < D; j += 256) orow[j] = xr[j] * r * w[j];
}

// ---------------------------------------------------------------------------
// Depthwise causal conv (K=4) + bias + SiLU.
// proj is (ROWS, 2*II); hs = proj[:, :II].  u out is (ROWS, II).
// ---------------------------------------------------------------------------
__global__ __launch_bounds__(256) void conv_silu_k(
    const float* __restrict__ proj, const float* __restrict__ cw,
    const float* __restrict__ cb, float* __restrict__ u, int total)
{
    int idx = blockIdx.x * 256 + threadIdx.x;
    if (idx >= total) return;
    int i  = idx % II;
    int bt = idx / II;
    int t  = bt % LL;
    float acc = cb[i];
    #pragma unroll
    for (int k = 0; k < KK; ++k) {
        int tt = t - (KK - 1) + k;
        if (tt >= 0)
            acc = fmaf(cw[i * KK + k], proj[(size_t)(bt - t + tt) * (2 * II) + i], acc);
    }
    u[idx] = acc / (1.f + expf(-acc));   // silu
}

// ---------------------------------------------------------------------------
// SSM selective scan.  One thread per (b, i) channel; N=16 state in registers.
// ssm rows are (dt_raw[48] | B[16] | C[16]).  dt buffer already softplus'ed.
// y = (scan_out + u*D) * silu(gate)
// ---------------------------------------------------------------------------
__global__ __launch_bounds__(256) void scan_k(
    const float* __restrict__ ssm,    // (ROWS, 80)
    const float* __restrict__ dt,     // (ROWS, II)
    const float* __restrict__ u,      // (ROWS, II)
    const float* __restrict__ proj,   // (ROWS, 2*II)  gate = cols [II, 2II)
    const float* __restrict__ alog,   // (II, NN)
    const float* __restrict__ dprm,   // (II)
    float* __restrict__ y)            // (ROWS, II)
{
    const int b = blockIdx.y;
    const int i = blockIdx.x * 256 + threadIdx.x;

    __shared__ float BC[LL][2 * NN];  // [t][0:16]=B, [16:32]=C
    for (int idx = threadIdx.x; idx < LL * 2 * NN; idx += 256) {
        int t = idx >> 5, j = idx & 31;
        BC[t][j] = ssm[(size_t)(b * LL + t) * (RR + 2 * NN) + RR + j];
    }
    __syncthreads();

    float A[NN], s[NN];
    #pragma unroll
    for (int n = 0; n < NN; ++n) { A[n] = -expf(alog[(size_t)i * NN + n]); s[n] = 0.f; }
    const float Dv = dprm[i];

    for (int t = 0; t < LL; ++t) {
        const size_t row = (size_t)(b * LL + t);
        const float dtv = dt[row * II + i];
        const float uv  = u[row * II + i];
        float yv = 0.f;
        #pragma unroll
        for (int n = 0; n < NN; ++n) {
            s[n] = expf(dtv * A[n]) * s[n] + dtv * BC[t][n] * uv;
            yv   = fmaf(s[n], BC[t][NN + n], yv);
        }
        yv += uv * Dv;
        const float g = proj[row * (2 * II) + II + i];
        yv *= g / (1.f + expf(-g));      // * silu(gate)
        y[row * II + i] = yv;
    }
}

// ---------------------------------------------------------------------------
// Head: split-K partial GEMM  out[b,n] += sum_{k in chunk} f[b,k]*W[k,n]
// grid (KS, B), block 256 (one n per thread). out must be pre-zeroed.
// ---------------------------------------------------------------------------
__global__ __launch_bounds__(256) void head_splitk_k(
    const float* __restrict__ f, const float* __restrict__ W,
    float* __restrict__ out, int Ktot, int KS)
{
    const int n = threadIdx.x;           // 256
    const int b = blockIdx.y;
    const int chunk = Ktot / KS;
    const int k0 = blockIdx.x * chunk;
    float acc = 0.f;
    for (int k = k0; k < k0 + chunk; ++k)
        acc = fmaf(f[(size_t)b * Ktot + k], W[(size_t)k * 256 + n], acc);
    atomicAdd(&out[b * 256 + n], acc);
}

__global__ __launch_bounds__(256) void zero_k(float* __restrict__ p, int n)
{
    int idx = blockIdx.x * 256 + threadIdx.x;
    if (idx < n) p[idx] = 0.f;
}

__global__ __launch_bounds__(256) void bias_relu_k(
    float* __restrict__ p, const float* __restrict__ bias, int n)
{
    int idx = blockIdx.x * 256 + threadIdx.x;
    if (idx < n) p[idx] = fmaxf(p[idx] + bias[idx & 255], 0.f);
}

// out[b] = sum_k o2[b*256+k]*w3[k] + b3[0]    (one block per b)
__global__ __launch_bounds__(256) void head_out_k(
    const float* __restrict__ o2, const float* __restrict__ w3,
    const float* __restrict__ b3, float* __restrict__ out)
{
    const int b = blockIdx.x;
    float v = o2[b * 256 + threadIdx.x] * w3[threadIdx.x];
    #pragma unroll
    for (int off = 32; off > 0; off >>= 1) v += __shfl_down(v, off, 64);
    __shared__ float wsum[4];
    if ((threadIdx.x & 63) == 0) wsum[threadIdx.x >> 6] = v;
    __syncthreads();
    if (threadIdx.x == 0)
        out[b] = wsum[0] + wsum[1] + wsum[2] + wsum[3] + b3[0];
}

// ---------------------------------------------------------------------------
// Host-side orchestration
// ---------------------------------------------------------------------------
static inline void launch_gemm(const float* A, int lda, const float* B, float* C,
                               const float* Cadd, const float* bias,
                               int M, int N, int K, int act, hipStream_t s)
{
    dim3 grid((N + 63) / 64, (M + 63) / 64);
    hipLaunchKernelGGL(gemm_f32, grid, dim3(256), 0, s, A, lda, B, C, Cadd, bias, M, N, K, act);
}

extern "C" void kernel_launch(void* const* d_in, const int* in_sizes, int n_in,
                              void* d_out, int out_size, void* d_ws, size_t ws_size,
                              hipStream_t stream)
{
    // ---- inputs (setup_inputs order) ----
    const float* x      = (const float*)d_in[0];   // (B,L,F)
    const float* w_in1  = (const float*)d_in[1];   // (13,256)
    const float* b_in1  = (const float*)d_in[2];
    const float* w_in2  = (const float*)d_in[3];   // (256,256)
    const float* b_in2  = (const float*)d_in[4];
    const float* w_in3  = (const float*)d_in[5];   // (256,768)
    const float* b_in3  = (const float*)d_in[6];
    const float* norm_w = (const float*)d_in[7];   // (NL,768)
    const float* ipw    = (const float*)d_in[8];   // (NL,768,3072)
    const float* cw     = (const float*)d_in[9];   // (NL,1536,4)
    const float* cb     = (const float*)d_in[10];  // (NL,1536)
    const float* xpw    = (const float*)d_in[11];  // (NL,1536,80)
    const float* dpw    = (const float*)d_in[12];  // (NL,48,1536)
    const float* dpb    = (const float*)d_in[13];  // (NL,1536)
    const float* alog   = (const float*)d_in[14];  // (NL,1536,16)
    const float* dprm   = (const float*)d_in[15];  // (NL,1536)
    const float* opw    = (const float*)d_in[16];  // (NL,1536,768)
    const float* nfw    = (const float*)d_in[17];  // (768)
    const float* w_o1   = (const float*)d_in[18];  // (46080,256)
    const float* b_o1   = (const float*)d_in[19];
    const float* w_o2   = (const float*)d_in[20];  // (256,256)
    const float* b_o2   = (const float*)d_in[21];
    const float* w_o3   = (const float*)d_in[22];  // (256,1)
    const float* b_o3   = (const float*)d_in[23];
    float* out = (float*)d_out;                    // (8,1) fp32

    // ---- workspace layout (floats) ----
    float* wsf = (float*)d_ws;
    size_t off = 0;
    float* h    = wsf + off; off += (size_t)ROWS * DM;        // 368640
    float* hn   = wsf + off; off += (size_t)ROWS * DM;        // 368640
    float* proj = wsf + off; off += (size_t)ROWS * 2 * II;    // 1474560
    float* u    = wsf + off; off += (size_t)ROWS * II;        // 737280
    float* ssm  = wsf + off; off += (size_t)ROWS * (RR+2*NN); // 38400
    float* dt   = wsf + off; off += (size_t)ROWS * II;        // 737280
    float* yb   = wsf + off; off += (size_t)ROWS * II;        // 737280
    float* t1   = wsf + off; off += (size_t)ROWS * 256;       // 122880
    float* t2   = wsf + off; off += (size_t)ROWS * 256;       // 122880
    float* o1   = wsf + off; off += BB * 256;                 // 2048
    float* o2   = wsf + off; off += BB * 256;                 // 2048
    (void)ws_size; (void)in_sizes; (void)n_in; (void)out_size;

    // ---- input MLP: (480,13)->(480,256)->(480,256)->(480,768) ----
    launch_gemm(x,  FF,  w_in1, t1, nullptr, b_in1, ROWS, 256, FF,  1, stream);
    launch_gemm(t1, 256, w_in2, t2, nullptr, b_in2, ROWS, 256, 256, 1, stream);
    launch_gemm(t2, 256, w_in3, h,  nullptr, b_in3, ROWS, DM,  256, 0, stream);

    // ---- 32 Mamba layers ----
    for (int l = 0; l < NL; ++l) {
        const float* nw_l   = norm_w + (size_t)l * DM;
        const float* ipw_l  = ipw    + (size_t)l * DM * 2 * II;
        const float* cw_l   = cw     + (size_t)l * II * KK;
        const float* cb_l   = cb     + (size_t)l * II;
        const float* xpw_l  = xpw    + (size_t)l * II * (RR + 2 * NN);
        const float* dpw_l  = dpw    + (size_t)l * RR * II;
        const float* dpb_l  = dpb    + (size_t)l * II;
        const float* alog_l = alog   + (size_t)l * II * NN;
        const float* dprm_l = dprm   + (size_t)l * II;
        const float* opw_l  = opw    + (size_t)l * II * DM;

        hipLaunchKernelGGL(rmsnorm_k, dim3(ROWS), dim3(256), 0, stream, h, nw_l, hn, DM);
        // in_proj: (480,768)@(768,3072)
        launch_gemm(hn, DM, ipw_l, proj, nullptr, nullptr, ROWS, 2 * II, DM, 0, stream);
        // conv + silu -> u (ROWS, II)
        hipLaunchKernelGGL(conv_silu_k, dim3((ROWS * II + 255) / 256), dim3(256), 0, stream,
                           proj, cw_l, cb_l, u, ROWS * II);
        // x_proj: (480,1536)@(1536,80)
        launch_gemm(u, II, xpw_l, ssm, nullptr, nullptr, ROWS, RR + 2 * NN, II, 0, stream);
        // dt: softplus( ssm[:,:48] @ (48,1536) + dpb )
        launch_gemm(ssm, RR + 2 * NN, dpw_l, dt, nullptr, dpb_l, ROWS, II, RR, 2, stream);
        // scan
        hipLaunchKernelGGL(scan_k, dim3(II / 256, BB), dim3(256), 0, stream,
                           ssm, dt, u, proj, alog_l, dprm_l, yb);
        // out_proj + residual: h = h + yb@(1536,768)
        launch_gemm(yb, II, opw_l, h, h, nullptr, ROWS, DM, II, 0, stream);
    }

    // ---- head ----
    hipLaunchKernelGGL(rmsnorm_k, dim3(ROWS), dim3(256), 0, stream, h, nfw, hn, DM);
    hipLaunchKernelGGL(zero_k, dim3(8), dim3(256), 0, stream, o1, BB * 256);
    // o1 = f @ w_o1  (split-K over 64 chunks of 720)
    hipLaunchKernelGGL(head_splitk_k, dim3(64, BB), dim3(256), 0, stream,
                       hn, w_o1, o1, LL * DM, 64);
    hipLaunchKernelGGL(bias_relu_k, dim3(8), dim3(256), 0, stream, o1, b_o1, BB * 256);
    // o2 = relu(o1 @ w_o2 + b_o2)
    launch_gemm(o1, 256, w_o2, o2, nullptr, b_o2, BB, 256, 256, 1, stream);
    // out = o2 @ w_o3 + b_o3
    hipLaunchKernelGGL(head_out_k, dim3(BB), dim3(256), 0, stream, o2, w_o3, b_o3, out);
}

// Round 3
// 5190.404 us; speedup vs baseline: 4.8127x; 4.8127x over previous
//
#include <hip/hip_runtime.h>
#include <cstddef>

#define BB   8
#define LL   60
#define FF   13
#define DM   768
#define II   1536
#define NN   16
#define RR   48
#define KK   4
#define NL   32
#define ROWS (BB * LL)          // 480

typedef __attribute__((ext_vector_type(8))) short short8;
typedef __attribute__((ext_vector_type(4))) float f32x4;

__device__ __forceinline__ unsigned short f2bf(float f) {
    union { float f; unsigned int u; } v; v.f = f;
    unsigned int u = v.u;
    unsigned int r = u + 0x7FFFu + ((u >> 16) & 1u);   // RNE
    return (unsigned short)(r >> 16);
}
__device__ __forceinline__ float bf2f(unsigned short h) {
    union { unsigned int u; float f; } v; v.u = ((unsigned int)h) << 16;
    return v.f;
}

// ---------------------------------------------------------------------------
// Transpose + split-convert: src (K,N) fp32 -> dstH/dstL (N,Kp) bf16 hi/lo.
// blockIdx.z = layer. Kp >= K, multiple of 32, zero-padded.
// ---------------------------------------------------------------------------
__global__ __launch_bounds__(256) void transpose_split_k(
    const float* __restrict__ src,
    unsigned short* __restrict__ dstH, unsigned short* __restrict__ dstL,
    int K, int N, int Kp)
{
    __shared__ unsigned short th[64][65];
    __shared__ unsigned short tl[64][65];
    const size_t so = (size_t)blockIdx.z * K * N;
    const size_t dof = (size_t)blockIdx.z * N * Kp;
    const int n0 = blockIdx.x * 64, k0 = blockIdx.y * 64;
    #pragma unroll
    for (int p = 0; p < 16; ++p) {
        int idx = p * 256 + threadIdx.x;
        int kk = idx >> 6, nn = idx & 63;
        int gk = k0 + kk, gn = n0 + nn;
        unsigned short h = 0, l = 0;
        if (gk < K && gn < N) {
            float f = src[so + (size_t)gk * N + gn];
            h = f2bf(f);
            l = f2bf(f - bf2f(h));
        }
        th[kk][nn] = h; tl[kk][nn] = l;
    }
    __syncthreads();
    #pragma unroll
    for (int p = 0; p < 16; ++p) {
        int idx = p * 256 + threadIdx.x;
        int nn = idx >> 6, kk = idx & 63;
        int gk = k0 + kk, gn = n0 + nn;
        if (gk < Kp && gn < N) {
            dstH[dof + (size_t)gn * Kp + gk] = th[kk][nn];
            dstL[dof + (size_t)gn * Kp + gk] = tl[kk][nn];
        }
    }
}

// ---------------------------------------------------------------------------
// Error-compensated bf16 MFMA GEMM (fp32-accurate):
//   C = act(A@B + bias)          (atomic=0)
//   atomicAdd(C, A@B)            (atomic=1, split-K over blockIdx.z)
// A: (M,K) fp32, row stride lda; split into hi/lo bf16 during staging.
// BhT/BlT: (N,Kp) bf16 pre-split weights (transposed, zero-padded to Kp).
// acc += Ah@Bl + Al@Bh + Ah@Bh  (AlBl dropped, ~2^-18 relative)
// 64x64 block tile, BK=32, 256 thr = 4 waves, wave tile 32x32.
// Requires K % 8 == 0.
// act: 0=none, 2=softplus
// ---------------------------------------------------------------------------
__global__ __launch_bounds__(256) void gemm_bf16s(
    const float* __restrict__ A, int lda,
    const unsigned short* __restrict__ BhT, const unsigned short* __restrict__ BlT,
    int Kp,
    float* __restrict__ C, const float* __restrict__ bias,
    int M, int N, int K, int act, int ksplit, int atomic)
{
    __shared__ unsigned short Ash[64 * 40];   // [m][k], stride 40 shorts
    __shared__ unsigned short Asl[64 * 40];
    __shared__ unsigned short Bsh[64 * 40];   // [n][k]
    __shared__ unsigned short Bsl[64 * 40];
    const int tid  = threadIdx.x;
    const int row0 = blockIdx.y * 64;
    const int col0 = blockIdx.x * 64;
    const int kbeg = blockIdx.z * ksplit;
    const int kend = (kbeg + ksplit < K) ? (kbeg + ksplit) : K;

    const int sm = tid >> 2;          // staging row (m or n), 0..63
    const int kc = (tid & 3) * 8;     // k-chunk within 32

    const int lane = tid & 63;
    const int wv   = tid >> 6;
    const int mo   = (wv & 1) * 32;
    const int no   = (wv >> 1) * 32;
    const int quad = lane >> 4;
    const int l15  = lane & 15;

    f32x4 acc00 = {0.f,0.f,0.f,0.f}, acc01 = acc00, acc10 = acc00, acc11 = acc00;

    for (int k0 = kbeg; k0 < kend; k0 += 32) {
        const int gk = k0 + kc;
        // ---- stage A tile (64 x 32): fp32 -> hi/lo bf16 ----
        {
            const int gm = row0 + sm;
            float f[8];
            if (gm < M && gk + 8 <= K) {
                float4 f0 = *(const float4*)(A + (size_t)gm * lda + gk);
                float4 f1 = *(const float4*)(A + (size_t)gm * lda + gk + 4);
                f[0]=f0.x; f[1]=f0.y; f[2]=f0.z; f[3]=f0.w;
                f[4]=f1.x; f[5]=f1.y; f[6]=f1.z; f[7]=f1.w;
            } else {
                #pragma unroll
                for (int j = 0; j < 8; ++j) f[j] = 0.f;
            }
            union { short8 v; unsigned short s[8]; } ph, pl;
            #pragma unroll
            for (int j = 0; j < 8; ++j) {
                unsigned short h = f2bf(f[j]);
                ph.s[j] = h;
                pl.s[j] = f2bf(f[j] - bf2f(h));
            }
            *(short8*)(Ash + sm * 40 + kc) = ph.v;
            *(short8*)(Asl + sm * 40 + kc) = pl.v;
        }
        // ---- stage B tile (64 n x 32 k) from BhT/BlT (N,Kp) ----
        {
            const int gn = col0 + sm;
            union { short8 v; uint4 u4; } bh, bl;
            if (gn < N) {
                bh.u4 = *(const uint4*)(BhT + (size_t)gn * Kp + gk);
                bl.u4 = *(const uint4*)(BlT + (size_t)gn * Kp + gk);
            } else {
                bh.u4 = make_uint4(0u,0u,0u,0u);
                bl.u4 = make_uint4(0u,0u,0u,0u);
            }
            *(short8*)(Bsh + sm * 40 + kc) = bh.v;
            *(short8*)(Bsl + sm * 40 + kc) = bl.v;
        }
        __syncthreads();
        short8 ah0 = *(const short8*)(Ash + (mo + l15)      * 40 + quad * 8);
        short8 ah1 = *(const short8*)(Ash + (mo + 16 + l15) * 40 + quad * 8);
        short8 al0 = *(const short8*)(Asl + (mo + l15)      * 40 + quad * 8);
        short8 al1 = *(const short8*)(Asl + (mo + 16 + l15) * 40 + quad * 8);
        short8 bh0 = *(const short8*)(Bsh + (no + l15)      * 40 + quad * 8);
        short8 bh1 = *(const short8*)(Bsh + (no + 16 + l15) * 40 + quad * 8);
        short8 bl0 = *(const short8*)(Bsl + (no + l15)      * 40 + quad * 8);
        short8 bl1 = *(const short8*)(Bsl + (no + 16 + l15) * 40 + quad * 8);
        acc00 = __builtin_amdgcn_mfma_f32_16x16x32_bf16(ah0, bl0, acc00, 0, 0, 0);
        acc01 = __builtin_amdgcn_mfma_f32_16x16x32_bf16(ah0, bl1, acc01, 0, 0, 0);
        acc10 = __builtin_amdgcn_mfma_f32_16x16x32_bf16(ah1, bl0, acc10, 0, 0, 0);
        acc11 = __builtin_amdgcn_mfma_f32_16x16x32_bf16(ah1, bl1, acc11, 0, 0, 0);
        acc00 = __builtin_amdgcn_mfma_f32_16x16x32_bf16(al0, bh0, acc00, 0, 0, 0);
        acc01 = __builtin_amdgcn_mfma_f32_16x16x32_bf16(al0, bh1, acc01, 0, 0, 0);
        acc10 = __builtin_amdgcn_mfma_f32_16x16x32_bf16(al1, bh0, acc10, 0, 0, 0);
        acc11 = __builtin_amdgcn_mfma_f32_16x16x32_bf16(al1, bh1, acc11, 0, 0, 0);
        acc00 = __builtin_amdgcn_mfma_f32_16x16x32_bf16(ah0, bh0, acc00, 0, 0, 0);
        acc01 = __builtin_amdgcn_mfma_f32_16x16x32_bf16(ah0, bh1, acc01, 0, 0, 0);
        acc10 = __builtin_amdgcn_mfma_f32_16x16x32_bf16(ah1, bh0, acc10, 0, 0, 0);
        acc11 = __builtin_amdgcn_mfma_f32_16x16x32_bf16(ah1, bh1, acc11, 0, 0, 0);
        __syncthreads();
    }

    // ---- epilogue: C/D layout col = lane&15, row = quad*4 + reg ----
    const f32x4* accs[4] = { &acc00, &acc01, &acc10, &acc11 };
    const int ioffs[4] = { 0, 0, 16, 16 };
    const int joffs[4] = { 0, 16, 0, 16 };
    #pragma unroll
    for (int q = 0; q < 4; ++q) {
        int gn = col0 + no + joffs[q] + l15;
        if (gn >= N) continue;
        #pragma unroll
        for (int r = 0; r < 4; ++r) {
            int gm = row0 + mo + ioffs[q] + quad * 4 + r;
            if (gm >= M) continue;
            float v = (*accs[q])[r];
            if (atomic) {
                atomicAdd(&C[(size_t)gm * N + gn], v);
            } else {
                if (bias) v += bias[gn];
                if (act == 2) v = (v > 20.f) ? v : log1pf(__expf(v));
                C[(size_t)gm * N + gn] = v;
            }
        }
    }
}

// ---------------------------------------------------------------------------
// fp32 tiled GEMM (MLP + head): C = act(A@B + bias)
// ---------------------------------------------------------------------------
__global__ __launch_bounds__(256) void gemm_f32(
    const float* __restrict__ A, int lda,
    const float* __restrict__ B,
    float* __restrict__ C,
    const float* __restrict__ bias,
    int M, int N, int K, int act)
{
    __shared__ float As[16][68];
    __shared__ float Bs[16][64];
    const int tid  = threadIdx.x;
    const int tx   = tid & 15;
    const int ty   = tid >> 4;
    const int row0 = blockIdx.y * 64;
    const int col0 = blockIdx.x * 64;

    float acc[4][4] = {};

    for (int k0 = 0; k0 < K; k0 += 16) {
        #pragma unroll
        for (int p = 0; p < 4; ++p) {
            int m  = ty + 16 * p;
            int gm = row0 + m, gk = k0 + tx;
            As[tx][m] = (gm < M && gk < K) ? A[(size_t)gm * lda + gk] : 0.f;
        }
        #pragma unroll
        for (int p = 0; p < 4; ++p) {
            int k  = (tid >> 6) + 4 * p;
            int n  = tid & 63;
            int gk = k0 + k, gn = col0 + n;
            Bs[k][n] = (gk < K && gn < N) ? B[(size_t)gk * N + gn] : 0.f;
        }
        __syncthreads();
        #pragma unroll
        for (int k = 0; k < 16; ++k) {
            float am[4], bn[4];
            #pragma unroll
            for (int i = 0; i < 4; ++i) am[i] = As[k][ty * 4 + i];
            #pragma unroll
            for (int j = 0; j < 4; ++j) bn[j] = Bs[k][tx * 4 + j];
            #pragma unroll
            for (int i = 0; i < 4; ++i)
                #pragma unroll
                for (int j = 0; j < 4; ++j)
                    acc[i][j] = fmaf(am[i], bn[j], acc[i][j]);
        }
        __syncthreads();
    }

    #pragma unroll
    for (int i = 0; i < 4; ++i) {
        int gm = row0 + ty * 4 + i;
        if (gm >= M) continue;
        #pragma unroll
        for (int j = 0; j < 4; ++j) {
            int gn = col0 + tx * 4 + j;
            if (gn >= N) continue;
            float v = acc[i][j];
            if (bias) v += bias[gn];
            if (act == 1) v = fmaxf(v, 0.f);
            C[(size_t)gm * N + gn] = v;
        }
    }
}

// ---------------------------------------------------------------------------
// RMSNorm (one block/row), fp32 out; optionally zeros a per-row slice of
// zero_ptr (pre-zeroes ssm for x_proj's atomic split-K).
// ---------------------------------------------------------------------------
__global__ __launch_bounds__(256) void rmsnorm_k(
    const float* __restrict__ x, const float* __restrict__ w,
    float* __restrict__ out,
    float* __restrict__ zero_ptr, int zero_n, int D)
{
    const int row = blockIdx.x;
    const float* xr = x + (size_t)row * D;

    if (zero_ptr) {
        for (int j = threadIdx.x; j < zero_n; j += 256)
            zero_ptr[(size_t)row * zero_n + j] = 0.f;
    }

    float ss = 0.f;
    for (int j = threadIdx.x; j < D; j += 256) { float v = xr[j]; ss = fmaf(v, v, ss); }
    #pragma unroll
    for (int off = 32; off > 0; off >>= 1) ss += __shfl_down(ss, off, 64);
    __shared__ float wsum[4];
    __shared__ float rstd_s;
    if ((threadIdx.x & 63) == 0) wsum[threadIdx.x >> 6] = ss;
    __syncthreads();
    if (threadIdx.x == 0) {
        float t = wsum[0] + wsum[1] + wsum[2] + wsum[3];
        rstd_s = 1.f / sqrtf(t / (float)D + 1e-5f);
    }
    __syncthreads();
    const float r = rstd_s;
    for (int j = threadIdx.x; j < D; j += 256)
        out[(size_t)row * D + j] = xr[j] * r * w[j];
}

// ---------------------------------------------------------------------------
// Depthwise causal conv (K=4) + bias + SiLU -> u (fp32)
// ---------------------------------------------------------------------------
__global__ __launch_bounds__(256) void conv_silu_k(
    const float* __restrict__ proj, const float* __restrict__ cw,
    const float* __restrict__ cb, float* __restrict__ u, int total)
{
    int idx = blockIdx.x * 256 + threadIdx.x;
    if (idx >= total) return;
    int i  = idx % II;
    int bt = idx / II;
    int t  = bt % LL;
    float acc = cb[i];
    #pragma unroll
    for (int k = 0; k < KK; ++k) {
        int tt = t - (KK - 1) + k;
        if (tt >= 0)
            acc = fmaf(cw[i * KK + k], proj[(size_t)(bt - t + tt) * (2 * II) + i], acc);
    }
    u[idx] = acc / (1.f + __expf(-acc));
}

// ---------------------------------------------------------------------------
// SSM scan. 64-thread blocks, one thread per (b,i), N=16 state in regs,
// next-step prefetch. fp32 out.
// ---------------------------------------------------------------------------
__global__ __launch_bounds__(64) void scan_k(
    const float* __restrict__ ssm,
    const float* __restrict__ dt,
    const float* __restrict__ u,
    const float* __restrict__ proj,
    const float* __restrict__ alog,
    const float* __restrict__ dprm,
    float* __restrict__ y)
{
    const int b = blockIdx.y;
    const int i = blockIdx.x * 64 + threadIdx.x;

    __shared__ float BC[LL][2 * NN];
    for (int idx = threadIdx.x; idx < LL * 2 * NN; idx += 64) {
        int t = idx >> 5, j = idx & 31;
        BC[t][j] = ssm[(size_t)(b * LL + t) * (RR + 2 * NN) + RR + j];
    }
    __syncthreads();

    float A[NN], s[NN];
    #pragma unroll
    for (int n = 0; n < NN; ++n) { A[n] = -__expf(alog[(size_t)i * NN + n]); s[n] = 0.f; }
    const float Dv = dprm[i];

    size_t r0 = (size_t)b * LL;
    float dtv = dt[r0 * II + i];
    float uv  = u[r0 * II + i];
    float g   = proj[r0 * (2 * II) + II + i];

    for (int t = 0; t < LL; ++t) {
        float dtn = dtv, un = uv, gnx = g;
        if (t + 1 < LL) {
            size_t rn = r0 + t + 1;
            dtn = dt[rn * II + i];
            un  = u[rn * II + i];
            gnx = proj[rn * (2 * II) + II + i];
        }
        float yv = 0.f;
        #pragma unroll
        for (int n = 0; n < NN; ++n) {
            s[n] = __expf(dtv * A[n]) * s[n] + dtv * BC[t][n] * uv;
            yv   = fmaf(s[n], BC[t][NN + n], yv);
        }
        yv += uv * Dv;
        yv *= g / (1.f + __expf(-g));
        y[(r0 + t) * II + i] = yv;
        dtv = dtn; uv = un; g = gnx;
    }
}

// ---------------------------------------------------------------------------
// Head kernels (fp32)
// ---------------------------------------------------------------------------
__global__ __launch_bounds__(256) void head_splitk_k(
    const float* __restrict__ f, const float* __restrict__ W,
    float* __restrict__ out, int Ktot, int KS)
{
    const int n = threadIdx.x;
    const int b = blockIdx.y;
    const int chunk = Ktot / KS;
    const int k0 = blockIdx.x * chunk;
    float acc = 0.f;
    for (int k = k0; k < k0 + chunk; ++k)
        acc = fmaf(f[(size_t)b * Ktot + k], W[(size_t)k * 256 + n], acc);
    atomicAdd(&out[b * 256 + n], acc);
}

__global__ __launch_bounds__(256) void zero_k(float* __restrict__ p, int n)
{
    int idx = blockIdx.x * 256 + threadIdx.x;
    if (idx < n) p[idx] = 0.f;
}

__global__ __launch_bounds__(256) void bias_relu_k(
    float* __restrict__ p, const float* __restrict__ bias, int n)
{
    int idx = blockIdx.x * 256 + threadIdx.x;
    if (idx < n) p[idx] = fmaxf(p[idx] + bias[idx & 255], 0.f);
}

__global__ __launch_bounds__(256) void head_out_k(
    const float* __restrict__ o2, const float* __restrict__ w3,
    const float* __restrict__ b3, float* __restrict__ out)
{
    const int b = blockIdx.x;
    float v = o2[b * 256 + threadIdx.x] * w3[threadIdx.x];
    #pragma unroll
    for (int off = 32; off > 0; off >>= 1) v += __shfl_down(v, off, 64);
    __shared__ float wsum[4];
    if ((threadIdx.x & 63) == 0) wsum[threadIdx.x >> 6] = v;
    __syncthreads();
    if (threadIdx.x == 0)
        out[b] = wsum[0] + wsum[1] + wsum[2] + wsum[3] + b3[0];
}

// ---------------------------------------------------------------------------
// Host orchestration
// ---------------------------------------------------------------------------
extern "C" void kernel_launch(void* const* d_in, const int* in_sizes, int n_in,
                              void* d_out, int out_size, void* d_ws, size_t ws_size,
                              hipStream_t stream)
{
    const float* x      = (const float*)d_in[0];
    const float* w_in1  = (const float*)d_in[1];
    const float* b_in1  = (const float*)d_in[2];
    const float* w_in2  = (const float*)d_in[3];
    const float* b_in2  = (const float*)d_in[4];
    const float* w_in3  = (const float*)d_in[5];
    const float* b_in3  = (const float*)d_in[6];
    const float* norm_w = (const float*)d_in[7];
    const float* ipw    = (const float*)d_in[8];
    const float* cw     = (const float*)d_in[9];
    const float* cb     = (const float*)d_in[10];
    const float* xpw    = (const float*)d_in[11];
    const float* dpw    = (const float*)d_in[12];
    const float* dpb    = (const float*)d_in[13];
    const float* alog   = (const float*)d_in[14];
    const float* dprm   = (const float*)d_in[15];
    const float* opw    = (const float*)d_in[16];
    const float* nfw    = (const float*)d_in[17];
    const float* w_o1   = (const float*)d_in[18];
    const float* b_o1   = (const float*)d_in[19];
    const float* w_o2   = (const float*)d_in[20];
    const float* b_o2   = (const float*)d_in[21];
    const float* w_o3   = (const float*)d_in[22];
    const float* b_o3   = (const float*)d_in[23];
    float* out = (float*)d_out;
    (void)in_sizes; (void)n_in; (void)out_size;

    // padded K for dt weights (K=48 -> 64); others are already 32-multiples
    const int DT_KP = 64;
    const int XP_N  = RR + 2 * NN;   // 80

    size_t off = 0;
    auto alloc = [&](size_t bytes) -> char* {
        off = (off + 255) & ~(size_t)255;
        char* p = (char*)d_ws + off;
        off += bytes;
        return p;
    };

    float* h    = (float*)alloc((size_t)ROWS * DM * 4);
    float* hn   = (float*)alloc((size_t)ROWS * DM * 4);
    float* proj = (float*)alloc((size_t)ROWS * 2 * II * 4);
    float* u    = (float*)alloc((size_t)ROWS * II * 4);
    float* ssm  = (float*)alloc((size_t)ROWS * XP_N * 4);
    float* dtb  = (float*)alloc((size_t)ROWS * II * 4);
    float* yb   = (float*)alloc((size_t)ROWS * II * 4);
    float* t1   = (float*)alloc((size_t)ROWS * 256 * 4);
    float* t2   = (float*)alloc((size_t)ROWS * 256 * 4);
    float* o1   = (float*)alloc(BB * 256 * 4);
    float* o2   = (float*)alloc(BB * 256 * 4);

    const size_t ipwT_n = (size_t)NL * (2 * II) * DM;    // (N=3072, Kp=768)
    const size_t opwT_n = (size_t)NL * DM * II;          // (N=768,  Kp=1536)
    const size_t xpwT_n = (size_t)NL * XP_N * II;        // (N=80,   Kp=1536)
    const size_t dpwT_n = (size_t)NL * II * DT_KP;       // (N=1536, Kp=64)
    const size_t full_bytes = 2 * 2 * (ipwT_n + opwT_n + xpwT_n + dpwT_n) + 8 * 256;
    const bool full = (off + full_bytes + 8192) <= ws_size;

    unsigned short *ipwTh, *ipwTl, *opwTh, *opwTl, *xpwTh, *xpwTl, *dpwTh, *dpwTl;
    if (full) {
        ipwTh = (unsigned short*)alloc(ipwT_n * 2);
        ipwTl = (unsigned short*)alloc(ipwT_n * 2);
        opwTh = (unsigned short*)alloc(opwT_n * 2);
        opwTl = (unsigned short*)alloc(opwT_n * 2);
        xpwTh = (unsigned short*)alloc(xpwT_n * 2);
        xpwTl = (unsigned short*)alloc(xpwT_n * 2);
        dpwTh = (unsigned short*)alloc(dpwT_n * 2);
        dpwTl = (unsigned short*)alloc(dpwT_n * 2);
        hipLaunchKernelGGL(transpose_split_k, dim3((2*II+63)/64, DM/64, NL), dim3(256), 0, stream,
                           ipw, ipwTh, ipwTl, DM, 2*II, DM);
        hipLaunchKernelGGL(transpose_split_k, dim3((DM+63)/64, II/64, NL), dim3(256), 0, stream,
                           opw, opwTh, opwTl, II, DM, II);
        hipLaunchKernelGGL(transpose_split_k, dim3((XP_N+63)/64, II/64, NL), dim3(256), 0, stream,
                           xpw, xpwTh, xpwTl, II, XP_N, II);
        hipLaunchKernelGGL(transpose_split_k, dim3((II+63)/64, DT_KP/64, NL), dim3(256), 0, stream,
                           dpw, dpwTh, dpwTl, RR, II, DT_KP);
    } else {
        ipwTh = (unsigned short*)alloc((ipwT_n / NL) * 2);
        ipwTl = (unsigned short*)alloc((ipwT_n / NL) * 2);
        opwTh = (unsigned short*)alloc((opwT_n / NL) * 2);
        opwTl = (unsigned short*)alloc((opwT_n / NL) * 2);
        xpwTh = (unsigned short*)alloc((xpwT_n / NL) * 2);
        xpwTl = (unsigned short*)alloc((xpwT_n / NL) * 2);
        dpwTh = (unsigned short*)alloc((dpwT_n / NL) * 2);
        dpwTl = (unsigned short*)alloc((dpwT_n / NL) * 2);
    }

    // ---- input MLP ----
    hipLaunchKernelGGL(gemm_f32, dim3(4, 8), dim3(256), 0, stream, x,  FF,  w_in1, t1, b_in1, ROWS, 256, FF,  1);
    hipLaunchKernelGGL(gemm_f32, dim3(4, 8), dim3(256), 0, stream, t1, 256, w_in2, t2, b_in2, ROWS, 256, 256, 1);
    hipLaunchKernelGGL(gemm_f32, dim3(12, 8), dim3(256), 0, stream, t2, 256, w_in3, h,  b_in3, ROWS, DM,  256, 0);

    // ---- 32 Mamba layers ----
    for (int l = 0; l < NL; ++l) {
        const float* nw_l   = norm_w + (size_t)l * DM;
        const float* cw_l   = cw     + (size_t)l * II * KK;
        const float* cb_l   = cb     + (size_t)l * II;
        const float* dpb_l  = dpb    + (size_t)l * II;
        const float* alog_l = alog   + (size_t)l * II * NN;
        const float* dprm_l = dprm   + (size_t)l * II;

        const unsigned short* ipwTh_l = full ? ipwTh + (size_t)l * (ipwT_n / NL) : ipwTh;
        const unsigned short* ipwTl_l = full ? ipwTl + (size_t)l * (ipwT_n / NL) : ipwTl;
        const unsigned short* opwTh_l = full ? opwTh + (size_t)l * (opwT_n / NL) : opwTh;
        const unsigned short* opwTl_l = full ? opwTl + (size_t)l * (opwT_n / NL) : opwTl;
        const unsigned short* xpwTh_l = full ? xpwTh + (size_t)l * (xpwT_n / NL) : xpwTh;
        const unsigned short* xpwTl_l = full ? xpwTl + (size_t)l * (xpwT_n / NL) : xpwTl;
        const unsigned short* dpwTh_l = full ? dpwTh + (size_t)l * (dpwT_n / NL) : dpwTh;
        const unsigned short* dpwTl_l = full ? dpwTl + (size_t)l * (dpwT_n / NL) : dpwTl;

        if (!full) {
            hipLaunchKernelGGL(transpose_split_k, dim3((2*II+63)/64, DM/64, 1), dim3(256), 0, stream,
                               ipw + (size_t)l*DM*2*II, (unsigned short*)ipwTh, (unsigned short*)ipwTl, DM, 2*II, DM);
            hipLaunchKernelGGL(transpose_split_k, dim3((DM+63)/64, II/64, 1), dim3(256), 0, stream,
                               opw + (size_t)l*II*DM, (unsigned short*)opwTh, (unsigned short*)opwTl, II, DM, II);
            hipLaunchKernelGGL(transpose_split_k, dim3((XP_N+63)/64, II/64, 1), dim3(256), 0, stream,
                               xpw + (size_t)l*II*XP_N, (unsigned short*)xpwTh, (unsigned short*)xpwTl, II, XP_N, II);
            hipLaunchKernelGGL(transpose_split_k, dim3((II+63)/64, DT_KP/64, 1), dim3(256), 0, stream,
                               dpw + (size_t)l*RR*II, (unsigned short*)dpwTh, (unsigned short*)dpwTl, RR, II, DT_KP);
        }

        // rmsnorm -> hn (fp32); also pre-zero ssm for x_proj's atomic split-K
        hipLaunchKernelGGL(rmsnorm_k, dim3(ROWS), dim3(256), 0, stream,
                           h, nw_l, hn, ssm, XP_N, DM);
        // in_proj: (480,768)@(768,3072) -> proj
        hipLaunchKernelGGL(gemm_bf16s, dim3(48, 8, 1), dim3(256), 0, stream,
                           hn, DM, ipwTh_l, ipwTl_l, DM, proj, (const float*)nullptr,
                           ROWS, 2 * II, DM, 0, DM, 0);
        // conv + silu -> u
        hipLaunchKernelGGL(conv_silu_k, dim3((ROWS * II + 255) / 256), dim3(256), 0, stream,
                           proj, cw_l, cb_l, u, ROWS * II);
        // x_proj: (480,1536)@(1536,80) -> ssm (split-K=8, atomic)
        hipLaunchKernelGGL(gemm_bf16s, dim3(2, 8, 8), dim3(256), 0, stream,
                           u, II, xpwTh_l, xpwTl_l, II, ssm, (const float*)nullptr,
                           ROWS, XP_N, II, 0, II / 8, 1);
        // dt: softplus(ssm[:, :48] @ (48,1536) + dpb) -> dtb
        hipLaunchKernelGGL(gemm_bf16s, dim3(24, 8, 1), dim3(256), 0, stream,
                           ssm, XP_N, dpwTh_l, dpwTl_l, DT_KP, dtb, dpb_l,
                           ROWS, II, RR, 2, DT_KP, 0);
        // scan -> yb
        hipLaunchKernelGGL(scan_k, dim3(II / 64, BB), dim3(64), 0, stream,
                           ssm, dtb, u, proj, alog_l, dprm_l, yb);
        // out_proj + residual: h += yb @ (1536,768)   (split-K=2, atomic)
        hipLaunchKernelGGL(gemm_bf16s, dim3(12, 8, 2), dim3(256), 0, stream,
                           yb, II, opwTh_l, opwTl_l, II, h, (const float*)nullptr,
                           ROWS, DM, II, 0, II / 2, 1);
    }

    // ---- head (fp32) ----
    hipLaunchKernelGGL(rmsnorm_k, dim3(ROWS), dim3(256), 0, stream,
                       h, nfw, hn, (float*)nullptr, 0, DM);
    hipLaunchKernelGGL(zero_k, dim3(8), dim3(256), 0, stream, o1, BB * 256);
    hipLaunchKernelGGL(head_splitk_k, dim3(64, BB), dim3(256), 0, stream,
                       hn, w_o1, o1, LL * DM, 64);
    hipLaunchKernelGGL(bias_relu_k, dim3(8), dim3(256), 0, stream, o1, b_o1, BB * 256);
    hipLaunchKernelGGL(gemm_f32, dim3(4, 1), dim3(256), 0, stream, o1, 256, w_o2, o2, b_o2, BB, 256, 256, 1);
    hipLaunchKernelGGL(head_out_k, dim3(BB), dim3(256), 0, stream, o2, w_o3, b_o3, out);
}